// Round 1
// 226.074 us; speedup vs baseline: 1.1182x; 1.1182x over previous
//
#include <hip/hip_runtime.h>
#include <hip/hip_bf16.h>

// HMLSTMCell2: B=65536, H=128, gates = 513-wide GEMM (K=384) + pointwise epilogue.
// Gate columns 0..511 via bf16 MFMA 16x16x32; column 512 (sz -> hard threshold z_new)
// in fp64 fused into A staging. Weights pre-converted/swizzled to bf16 in d_ws.
// R3->R4: latency restructure. Old: acc[4][8]=128 AGPR + 128 VGPR = 256/wave ->
// 2 waves/SIMD -> 1 block/CU, and 24 full-drain __syncthreads per block (vmcnt(0)
// before every barrier) -> 70% issue-idle (MfmaUtil 8.3, VALUBusy 22.6, Occ 20%).
// New: MT=64, per-wave tile 32x128 (acc[2][8]=64) targeting <=128 regs -> 2
// blocks/CU (16 waves, independent barrier groups); W and A double-buffered with
// ONE raw s_barrier per chunk and counted vmcnt (prefetch distance 1 chunk for
// both A-reg loads and W global_load_lds) so no HBM/L2 round-trip is ever on the
// barrier critical path.

#define MT   64          // rows per block
#define BK   32          // K chunk
#define NKC  12          // 384 / 32
#define NT   512         // threads per block
#define COFF 8388608     // c_new offset in d_out (65536*128)
#define ZOFF 16777216    // z_new offset (2*65536*128)

using short8 = __attribute__((ext_vector_type(8))) short;  // 8 bf16 (4 VGPR)
using f32x4  = __attribute__((ext_vector_type(4))) float;  // MFMA acc frag

__device__ __forceinline__ unsigned short f2bf(float f) {
  union { float f; unsigned u; } v; v.f = f;
  unsigned r = (v.u + 0x7FFFu + ((v.u >> 16) & 1u)) >> 16;  // RNE truncate
  return (unsigned short)r;
}

__device__ __forceinline__ void async_copy16(const void* g, void* l) {
  __builtin_amdgcn_global_load_lds(
      (const __attribute__((address_space(1))) unsigned int*)g,
      (__attribute__((address_space(3))) unsigned int*)l, 16, 0, 0);
}

__device__ __forceinline__ float sigm(float x)     { return 1.f / (1.f + __expf(-x)); }
__device__ __forceinline__ float tanh_fast(float x){ return 1.f - 2.f / (1.f + __expf(2.f * x)); }

// d_ws layout: bf16, element ((c*512 + n)*4 + (u ^ ((n>>1)&3)))*8 + j holds
// Wc[k = c*32 + u*8 + j][n], Wc = [W; R; U] (cols 0..511). The XOR pre-swizzle
// uses (n>>1)&3 because the bank-relevant low bit of the 64 B row stride is n&1;
// this spreads ds_read_b128 start banks 2/bank (free per m136).
__global__ void prep_weights(const float* __restrict__ W, const float* __restrict__ R,
                             const float* __restrict__ U, unsigned short* __restrict__ Wt) {
  int idx = blockIdx.x * blockDim.x + threadIdx.x;   // 0 .. 24575
  if (idx >= NKC * 512 * 4) return;
  int up = idx & 3;            // physical 16B unit within row
  int n  = (idx >> 2) & 511;   // output column
  int c  = idx >> 11;          // K chunk
  int ul = up ^ ((n >> 1) & 3);// logical unit
  int k0 = c * 32 + ul * 8;    // global k of first element
  const float* src; int kb;
  if (k0 < 128)      { src = W; kb = 0;   }
  else if (k0 < 256) { src = R; kb = 128; }
  else               { src = U; kb = 256; }
  const float* colp = src + (size_t)(k0 - kb) * 513 + n;
  unsigned short vs[8];
  #pragma unroll
  for (int j = 0; j < 8; ++j) vs[j] = f2bf(colp[j * 513]);
  uint4 o;
  o.x = (unsigned)vs[0] | ((unsigned)vs[1] << 16);
  o.y = (unsigned)vs[2] | ((unsigned)vs[3] << 16);
  o.z = (unsigned)vs[4] | ((unsigned)vs[5] << 16);
  o.w = (unsigned)vs[6] | ((unsigned)vs[7] << 16);
  reinterpret_cast<uint4*>(Wt)[idx] = o;
}

__global__ __launch_bounds__(NT, 4)
void hmlstm_main(const float* __restrict__ hb, const float* __restrict__ hs,
                 const float* __restrict__ ht, const float* __restrict__ cs,
                 const float* __restrict__ zp, const float* __restrict__ zbp,
                 const float* __restrict__ W,  const float* __restrict__ R,
                 const float* __restrict__ U,  const float* __restrict__ b,
                 const unsigned short* __restrict__ Wt, float* __restrict__ out)
{
  __shared__ unsigned short ldsW[2][512 * BK];   // 64 KB, double-buffered W chunks
  __shared__ unsigned short ldsA[2][MT * BK];    // 8 KB, double-buffered A chunks
  __shared__ float  ldsWL[384];                  // fp32 col-512 weights (for sz)
  __shared__ double ldsSZ[NT];                   // sz partial reduce (fp64)
  // total 79360 B <= 81920 -> 2 blocks/CU by LDS

  const int tid  = threadIdx.x;
  const int l    = tid & 63;
  const int wv   = tid >> 6;   // 0..7
  const int ws   = wv & 3;     // col slice
  const int wr   = wv >> 2;    // row half (32 rows)
  const int q    = l >> 4;     // quad 0..3
  const int lr   = l & 15;
  const int row0 = blockIdx.x * MT;

  // stage fp32 column-512 weights (sz path)
  for (int k = tid; k < 384; k += NT) {
    ldsWL[k] = (k < 128) ? W[k * 513 + 512]
             : (k < 256) ? R[(k - 128) * 513 + 512]
                         : U[(k - 256) * 513 + 512];
  }

  // A-staging assignment: thread -> (row m, 4-float group p); fixed across chunks
  const int m    = tid >> 3;       // 0..63
  const int p    = tid & 7;        // 0..7
  const int arow = row0 + m;
  const float zbv = zbp[arow];
  const float zv  = zp[arow];
  double szacc = 0.0;

  f32x4 acc[2][8];
  {
    f32x4 zf = {0.f, 0.f, 0.f, 0.f};
    #pragma unroll
    for (int i = 0; i < 2; ++i)
      #pragma unroll
      for (int j = 0; j < 8; ++j) acc[i][j] = zf;
  }

  // swizzled 8B half-slot for A staging (16B-unit swizzle identical to read side)
  const int aW = m * BK + (((p >> 1) ^ ((m >> 1) & 3)) * 8) + (p & 1) * 4;
  const size_t rowb = (size_t)arow * 128 + p * 4;

  auto loadA = [&](int c) -> f32x4 {
    const float* src = (c < 4) ? hb : (c < 8) ? hs : ht;
    return *(const f32x4*)(src + rowb + (c & 3) * 32);
  };
  auto consumeA = [&](int c, f32x4 v, int buf) {
    const float scale = (c < 4) ? zbv : (c < 8) ? 1.f : zv;
    v *= scale;
    const float* wl = ldsWL + c * 32 + p * 4;
    szacc += (double)v.x * wl[0] + (double)v.y * wl[1]
           + (double)v.z * wl[2] + (double)v.w * wl[3];
    uint2 pk;
    pk.x = (unsigned)f2bf(v.x) | ((unsigned)f2bf(v.y) << 16);
    pk.y = (unsigned)f2bf(v.z) | ((unsigned)f2bf(v.w) << 16);
    *(uint2*)&ldsA[buf][aW] = pk;
  };
  auto stageW = [&](int c, int buf) {
    const unsigned short* gW = Wt + c * (512 * BK);
    #pragma unroll
    for (int r = 0; r < 4; ++r) {
      int eo = (wv * 4 + r) * 512;                 // 8 waves x 4 rounds x 512 elem
      async_copy16(gW + eo + l * 8, &ldsW[buf][eo]);
    }
  };

  // ---- prologue: A(0) in flight over ldsWL barrier; stage W0/W1, A1 in flight ----
  f32x4 a0 = loadA(0);
  asm volatile("s_waitcnt lgkmcnt(0)" ::: "memory");
  __builtin_amdgcn_s_barrier();                    // ldsWL ready
  consumeA(0, a0, 0);                              // compiler waits vmcnt(0) for a0
  stageW(0, 0);                                    // 4 vmem
  f32x4 ain = loadA(1);                            // 1 vmem
  stageW(1, 1);                                    // 4 vmem -> queue [W0x4, A1, W1x4]
  asm volatile("s_waitcnt vmcnt(5)" ::: "memory"); // W0 arrived; A1+W1 stay in flight
  asm volatile("s_waitcnt lgkmcnt(0)" ::: "memory");
  __builtin_amdgcn_s_barrier();                    // Abuf0 + Wbuf0 visible

  // ---- main loop: ONE barrier/chunk, counted vmcnt, prefetch distance 1 ----
  // invariant at iter top: queue = [A(kc+1), W(kc+1)x4]
  #pragma unroll 1
  for (int kc = 0; kc < NKC; ++kc) {
    const int cur = kc & 1;
    // MFMA: wave tile 32 rows x {4 gates x 32 cols}; K=32
    short8 af[2];
    #pragma unroll
    for (int s = 0; s < 2; ++s) {
      int mr = wr * 32 + s * 16 + lr;              // A[m = lane&15][k = q*8+j]
      af[s] = *(const short8*)&ldsA[cur][mr * BK + ((q ^ ((mr >> 1) & 3)) * 8)];
    }
    #pragma unroll
    for (int tn = 0; tn < 8; ++tn) {
      int nc = (tn >> 1) * 128 + ws * 32 + (tn & 1) * 16 + lr;  // gate-spread cols
      short8 bf = *(const short8*)&ldsW[cur][nc * BK + ((q ^ ((nc >> 1) & 3)) * 8)];
      acc[0][tn] = __builtin_amdgcn_mfma_f32_16x16x32_bf16(af[0], bf, acc[0][tn], 0, 0, 0);
      acc[1][tn] = __builtin_amdgcn_mfma_f32_16x16x32_bf16(af[1], bf, acc[1][tn], 0, 0, 0);
    }
    if (kc < NKC - 1) {
      consumeA(kc + 1, ain, cur ^ 1);              // compiler waits vmcnt(4): A done, W in flight
      if (kc < NKC - 2) {
        ain = loadA(kc + 2);                       // queue [W(kc+1)x4, A(kc+2)]
        asm volatile("s_waitcnt vmcnt(1)" ::: "memory");   // W(kc+1) arrived
      } else {
        asm volatile("s_waitcnt vmcnt(0)" ::: "memory");   // last W drain
      }
      asm volatile("s_waitcnt lgkmcnt(0)" ::: "memory");   // A ds_write visible
      __builtin_amdgcn_s_barrier();
      if (kc < NKC - 2) stageW(kc + 2, cur);       // safe: all waves done with Wbuf[cur]
    }
  }

  // ---- z_new: fp64 sz reduce (8 partials per row), hard threshold sz > 0 ----
  ldsSZ[tid] = szacc;
  __syncthreads();
  if (tid < MT) {
    const double* pz = &ldsSZ[tid * 8];
    double ss = ((pz[0] + pz[1]) + (pz[2] + pz[3])) + ((pz[4] + pz[5]) + (pz[6] + pz[7]));
    float s = (float)ss + b[512];
    out[ZOFF + row0 + tid] = (s > 0.f) ? 1.f : 0.f;
  }

  // ---- epilogue: all four gates for (row,col) live in this lane's acc ----
  float bias[2][4];
  #pragma unroll
  for (int th = 0; th < 2; ++th) {
    const int col = ws * 32 + th * 16 + lr;
    bias[th][0] = b[col];       bias[th][1] = b[128 + col];
    bias[th][2] = b[256 + col]; bias[th][3] = b[384 + col];
  }
  #pragma unroll
  for (int s = 0; s < 2; ++s) {
    #pragma unroll
    for (int r = 0; r < 4; ++r) {
      const int row = row0 + wr * 32 + s * 16 + q * 4 + r;  // C/D: row=quad*4+reg
      const float zr  = zp[row];
      const float zbr = zbp[row];
      const size_t rowoff = (size_t)row * 128;
      #pragma unroll
      for (int th = 0; th < 2; ++th) {
        const int col = ws * 32 + th * 16 + lr;             // C/D: col=lane&15
        const size_t off = rowoff + col;
        float si = acc[s][0 + th][r] + bias[th][0];
        float sg = acc[s][2 + th][r] + bias[th][1];
        float so = acc[s][4 + th][r] + bias[th][2];
        float sf = acc[s][6 + th][r] + bias[th][3];
        float iv = sigm(si);
        float gv = tanh_fast(sg);
        float ov = sigm(so);
        float fv = sigm(sf);
        float ig = iv * gv;
        float cv = cs[off];
        float hv = hs[off];
        float cn = (zr == 1.f) ? ig : ((zbr == 0.f) ? cv : cv * fv + ig);
        float hn = (zr == 0.f && zbr == 0.f) ? hv : tanh_fast(cn) * ov;
        out[off]        = hn;
        out[COFF + off] = cn;
      }
    }
  }
}

extern "C" void kernel_launch(void* const* d_in, const int* in_sizes, int n_in,
                              void* d_out, int out_size, void* d_ws, size_t ws_size,
                              hipStream_t stream) {
  const float* hb  = (const float*)d_in[0];
  const float* hs  = (const float*)d_in[1];
  const float* ht  = (const float*)d_in[2];
  const float* cs  = (const float*)d_in[3];
  const float* zp  = (const float*)d_in[4];
  const float* zbp = (const float*)d_in[5];
  const float* W   = (const float*)d_in[6];
  const float* R   = (const float*)d_in[7];
  const float* U   = (const float*)d_in[8];
  const float* b   = (const float*)d_in[9];
  unsigned short* Wt = (unsigned short*)d_ws;   // 12*512*32*2 = 393216 B
  float* out = (float*)d_out;

  prep_weights<<<dim3(96), dim3(256), 0, stream>>>(W, R, U, Wt);
  hmlstm_main<<<dim3(65536 / MT), dim3(NT), 0, stream>>>(
      hb, hs, ht, cs, zp, zbp, W, R, U, b, Wt, out);
}